// Round 1
// baseline (995.785 us; speedup 1.0000x reference)
//
#include <hip/hip_runtime.h>
#include <hip/hip_bf16.h>

// Problem constants (from reference)
#define D_DIM 1024
#define H_DIMN 1024
#define N_TOK 1024   // B*M = 64*16
#define N_EXP 16
#define TOPK  4
#define N_PAIR (N_TOK*TOPK)   // 4096
#define B_SZ  64
#define OUT_SZ 10

// ---------------- workspace layout (bytes) ----------------
static constexpr size_t WS_TKIDX   = 0;         // int[4096]
static constexpr size_t WS_TKGATE  = 16384;     // float[4096]
static constexpr size_t WS_COUNTS  = 32768;     // int[16]
static constexpr size_t WS_OFFSETS = 33024;     // int[17]
static constexpr size_t WS_CURSORS = 33280;     // int[16]
static constexpr size_t WS_IMP     = 33536;     // float[16]
static constexpr size_t WS_PERMTOK = 33792;     // int[4096]
static constexpr size_t WS_PAIRROW = 50176;     // int[4096]
static constexpr size_t WS_H       = 131072;                         // float[4096*1024]
static constexpr size_t WS_O       = WS_H + (size_t)N_PAIR*H_DIMN*4; // float[4096*1024]
// total ~33.7 MB

// ---------------- init: zero atomics ----------------
__global__ __launch_bounds__(64) void init_kernel(int* counts, float* imp) {
  int t = threadIdx.x;
  if (t < N_EXP) { counts[t] = 0; imp[t] = 0.f; }
}

// ---------------- gating: logits -> top4 -> softmax ----------------
// one wave per token; 4 waves per block; grid 256
__global__ __launch_bounds__(256) void gate_kernel(
    const float* __restrict__ x, const float* __restrict__ wg,
    int* __restrict__ tk_idx, float* __restrict__ tk_gates,
    int* __restrict__ counts, float* __restrict__ imp)
{
  int wave = threadIdx.x >> 6, lane = threadIdx.x & 63;
  int n = blockIdx.x * 4 + wave;
  const float* xr = x + (size_t)n * D_DIM;
  float xv[16];
  #pragma unroll
  for (int i = 0; i < 16; i++) xv[i] = xr[lane + 64*i];

  float lg[N_EXP];
  #pragma unroll
  for (int e = 0; e < N_EXP; e++) {
    float s = 0.f;
    #pragma unroll
    for (int i = 0; i < 16; i++) s += xv[i] * wg[(lane + 64*i)*N_EXP + e];
    #pragma unroll
    for (int off = 32; off; off >>= 1) s += __shfl_xor(s, off);
    lg[e] = s;   // all lanes hold full logit
  }

  // top-4; ties -> smallest index (matches jax.lax.top_k)
  float tv[TOPK]; int ti[TOPK];
  #pragma unroll
  for (int k = 0; k < TOPK; k++) {
    float mv = -3.4e38f; int mi = 0;
    #pragma unroll
    for (int e = 0; e < N_EXP; e++) if (lg[e] > mv) { mv = lg[e]; mi = e; }
    tv[k] = mv; ti[k] = mi; lg[mi] = -3.4e38f;
  }
  float mx = tv[0];
  float ex[TOPK]; float ssum = 0.f;
  #pragma unroll
  for (int k = 0; k < TOPK; k++) { ex[k] = expf(tv[k] - mx); ssum += ex[k]; }
  float inv = 1.f / ssum;

  if (lane < TOPK) {
    tk_idx  [n*TOPK + lane] = ti[lane];
    tk_gates[n*TOPK + lane] = ex[lane] * inv;
  }
  if (lane == 0) {
    #pragma unroll
    for (int k = 0; k < TOPK; k++) {
      atomicAdd(&counts[ti[k]], 1);
      atomicAdd(&imp[ti[k]], ex[k] * inv);
    }
  }
}

// ---------------- scan offsets + aux loss ----------------
__global__ __launch_bounds__(64) void scan_loss_kernel(
    const int* __restrict__ counts, const float* __restrict__ imp,
    int* __restrict__ offsets, int* __restrict__ cursors, float* __restrict__ out)
{
  if (threadIdx.x == 0) {
    int off = 0;
    for (int e = 0; e < N_EXP; e++) { offsets[e] = off; cursors[e] = off; off += counts[e]; }
    offsets[N_EXP] = off;
    float mi = 0.f, ml = 0.f;
    for (int e = 0; e < N_EXP; e++) { mi += imp[e]; ml += (float)counts[e]; }
    mi *= (1.f/N_EXP); ml *= (1.f/N_EXP);
    float vi = 0.f, vl = 0.f;
    for (int e = 0; e < N_EXP; e++) {
      float di = imp[e] - mi;           vi += di*di;
      float dl = (float)counts[e] - ml; vl += dl*dl;
    }
    vi *= (1.f/(N_EXP-1)); vl *= (1.f/(N_EXP-1));   // ddof=1
    out[640] = 0.01f * (vi/(mi*mi + 1e-10f) + vl/(ml*ml + 1e-10f));
  }
}

// ---------------- scatter tokens into expert-grouped rows ----------------
// row order within an expert is nondeterministic (atomics) but every row is
// computed independently and gathered back per-token via pair_row -> output
// is deterministic.
__global__ __launch_bounds__(256) void scatter_kernel(
    const int* __restrict__ tk_idx, int* __restrict__ cursors,
    int* __restrict__ perm_tok, int* __restrict__ pair_row)
{
  int p = blockIdx.x * 256 + threadIdx.x;   // 0..4095
  int e = tk_idx[p];
  int row = atomicAdd(&cursors[e], 1);
  perm_tok[row] = p >> 2;
  pair_row[p] = row;
}

// ---------------- grouped fp32 GEMM ----------------
// C[rows, 1024] = A[rows, 1024] @ W[e] + bias[e]  (optional relu)
// tile 128x128, BK=8, 256 threads, 8x8 micro-tile/thread
// grid.x = expert*8 + row_slot (slots cover up to 1024 rows/expert), grid.y = col tile (8)
template<int GATHER, int RELU>
__global__ __launch_bounds__(256) void ffn_gemm(
    const float* __restrict__ Asrc,
    const float* __restrict__ W,
    const float* __restrict__ bias,
    float* __restrict__ Out,
    const int* __restrict__ offsets,
    const int* __restrict__ perm_tok)
{
  __shared__ float As[8][128];   // As[k][m] (transposed for row-vector reads)
  __shared__ float Bs[8][128];

  const int e    = blockIdx.x >> 3;
  const int slot = blockIdx.x & 7;
  const int colbase = blockIdx.y * 128;
  const int row0 = offsets[e];
  const int row_end = offsets[e+1];
  const int row_start = row0 + slot * 128;
  if (row_start >= row_end) return;
  const int rows_here = min(128, row_end - row_start);

  const int tid = threadIdx.x;
  // A staging: thread -> (row = tid/2, k-offset = (tid&1)*4)
  const int arow = tid >> 1;
  const int ac   = (tid & 1) * 4;
  const bool a_valid = (arow < rows_here);
  const float* a_base = nullptr;
  if (a_valid) {
    int r = row_start + arow;
    int src_row = GATHER ? perm_tok[r] : r;
    a_base = Asrc + (size_t)src_row * D_DIM + ac;
  }
  // B staging: thread -> (k = tid/32, col4 = (tid&31)*4); coalesced 512B/row
  const int bk = tid >> 5;
  const int bc = (tid & 31) * 4;
  const float* b_base = W + (size_t)e*D_DIM*H_DIMN + (size_t)bk*H_DIMN + colbase + bc;

  const int tm = tid >> 4;   // 0..15
  const int tn = tid & 15;   // 0..15

  float acc[8][8];
  #pragma unroll
  for (int i = 0; i < 8; i++)
    #pragma unroll
    for (int j = 0; j < 8; j++) acc[i][j] = 0.f;

  // register-prefetch double-stage
  float4 av = make_float4(0.f,0.f,0.f,0.f);
  if (a_valid) av = *(const float4*)(a_base);
  float4 bv = *(const float4*)(b_base);

  for (int kk = 0; kk < D_DIM; kk += 8) {
    __syncthreads();
    As[ac+0][arow] = av.x;
    As[ac+1][arow] = av.y;
    As[ac+2][arow] = av.z;
    As[ac+3][arow] = av.w;
    *(float4*)&Bs[bk][bc] = bv;
    __syncthreads();
    if (kk + 8 < D_DIM) {
      av = make_float4(0.f,0.f,0.f,0.f);
      if (a_valid) av = *(const float4*)(a_base + kk + 8);
      bv = *(const float4*)(b_base + (size_t)(kk + 8) * H_DIMN);
    }
    #pragma unroll
    for (int k = 0; k < 8; k++) {
      float4 a0 = *(const float4*)&As[k][tm*8];
      float4 a1 = *(const float4*)&As[k][tm*8+4];
      float4 b0 = *(const float4*)&Bs[k][tn*8];
      float4 b1 = *(const float4*)&Bs[k][tn*8+4];
      float ar[8] = {a0.x,a0.y,a0.z,a0.w,a1.x,a1.y,a1.z,a1.w};
      float br[8] = {b0.x,b0.y,b0.z,b0.w,b1.x,b1.y,b1.z,b1.w};
      #pragma unroll
      for (int i = 0; i < 8; i++)
        #pragma unroll
        for (int j = 0; j < 8; j++)
          acc[i][j] = fmaf(ar[i], br[j], acc[i][j]);
    }
  }

  // epilogue
  const int col = colbase + tn*8;
  const float4 bi0 = *(const float4*)&bias[e*H_DIMN + col];
  const float4 bi1 = *(const float4*)&bias[e*H_DIMN + col + 4];
  #pragma unroll
  for (int i = 0; i < 8; i++) {
    int lr = tm*8 + i;
    if (lr < rows_here) {
      size_t r = (size_t)(row_start + lr);
      float4 o0, o1;
      o0.x = acc[i][0]+bi0.x; o0.y = acc[i][1]+bi0.y; o0.z = acc[i][2]+bi0.z; o0.w = acc[i][3]+bi0.w;
      o1.x = acc[i][4]+bi1.x; o1.y = acc[i][5]+bi1.y; o1.z = acc[i][6]+bi1.z; o1.w = acc[i][7]+bi1.w;
      if (RELU) {
        o0.x = fmaxf(o0.x,0.f); o0.y = fmaxf(o0.y,0.f); o0.z = fmaxf(o0.z,0.f); o0.w = fmaxf(o0.w,0.f);
        o1.x = fmaxf(o1.x,0.f); o1.y = fmaxf(o1.y,0.f); o1.z = fmaxf(o1.z,0.f); o1.w = fmaxf(o1.w,0.f);
      }
      *(float4*)&Out[r*H_DIMN + col]     = o0;
      *(float4*)&Out[r*H_DIMN + col + 4] = o1;
    }
  }
}

// ---------------- gather per-token, sum over M, LayerNorm, scores head ----------------
// one block per batch b (64 blocks), 256 threads; thread owns 4 d's
__global__ __launch_bounds__(256) void moe_ln_kernel(
    const float* __restrict__ O,
    const float* __restrict__ tk_gates,
    const int* __restrict__ pair_row,
    const float* __restrict__ ln_w, const float* __restrict__ ln_b,
    const float* __restrict__ W_los, const float* __restrict__ b_los,
    float* __restrict__ out)
{
  __shared__ float fin[D_DIM];
  __shared__ float redx[256];
  __shared__ float redy[256];
  const int b = blockIdx.x, tid = threadIdx.x;
  float4 acc = make_float4(0.f,0.f,0.f,0.f);
  for (int m = 0; m < 16; m++) {
    int n = b*16 + m;
    #pragma unroll
    for (int k = 0; k < TOPK; k++) {
      int p = n*TOPK + k;
      float g = tk_gates[p];
      int row = pair_row[p];
      float4 v = *(const float4*)&O[(size_t)row*D_DIM + tid*4];
      acc.x = fmaf(g, v.x, acc.x);
      acc.y = fmaf(g, v.y, acc.y);
      acc.z = fmaf(g, v.z, acc.z);
      acc.w = fmaf(g, v.w, acc.w);
    }
  }
  float s  = acc.x + acc.y + acc.z + acc.w;
  float s2 = acc.x*acc.x + acc.y*acc.y + acc.z*acc.z + acc.w*acc.w;
  redx[tid] = s; redy[tid] = s2;
  __syncthreads();
  for (int off = 128; off > 0; off >>= 1) {
    if (tid < off) { redx[tid] += redx[tid+off]; redy[tid] += redy[tid+off]; }
    __syncthreads();
  }
  float mean = redx[0] * (1.f/D_DIM);
  float var  = redy[0] * (1.f/D_DIM) - mean*mean;   // ddof=0 (jnp.var default)
  float rstd = rsqrtf(var + 1e-5f);

  int d0 = tid*4;
  fin[d0+0] = (acc.x - mean)*rstd*ln_w[d0+0] + ln_b[d0+0];
  fin[d0+1] = (acc.y - mean)*rstd*ln_w[d0+1] + ln_b[d0+1];
  fin[d0+2] = (acc.z - mean)*rstd*ln_w[d0+2] + ln_b[d0+2];
  fin[d0+3] = (acc.w - mean)*rstd*ln_w[d0+3] + ln_b[d0+3];
  __syncthreads();

  if (tid < 64) {
    for (int o = 0; o < OUT_SZ; o++) {
      float p = 0.f;
      for (int d = tid; d < D_DIM; d += 64) p = fmaf(fin[d], W_los[d*OUT_SZ + o], p);
      #pragma unroll
      for (int off = 32; off; off >>= 1) p += __shfl_xor(p, off);
      if (tid == 0) out[b*OUT_SZ + o] = p + b_los[o];
    }
  }
}

// ---------------- pred_loss = mean((scores - true_y)^2) ----------------
__global__ __launch_bounds__(256) void pred_kernel(
    const float* __restrict__ true_y, float* __restrict__ out)
{
  __shared__ float red[256];
  int tid = threadIdx.x;
  float s = 0.f;
  for (int i = tid; i < B_SZ*OUT_SZ; i += 256) {
    float df = out[i] - true_y[i];
    s = fmaf(df, df, s);
  }
  red[tid] = s;
  __syncthreads();
  for (int off = 128; off > 0; off >>= 1) {
    if (tid < off) red[tid] += red[tid+off];
    __syncthreads();
  }
  if (tid == 0) out[641] = red[0] * (1.f/(B_SZ*OUT_SZ));
}

// ---------------- launch ----------------
extern "C" void kernel_launch(void* const* d_in, const int* in_sizes, int n_in,
                              void* d_out, int out_size, void* d_ws, size_t ws_size,
                              hipStream_t stream) {
  const float* x      = (const float*)d_in[0];   // mm_embed (64,16,1024)
  const float* wg     = (const float*)d_in[1];   // w_gate (1024,16)
  const float* W1     = (const float*)d_in[2];   // (16,1024,1024)
  const float* b1     = (const float*)d_in[3];   // (16,1024)
  const float* W2     = (const float*)d_in[4];   // (16,1024,1024)
  const float* b2     = (const float*)d_in[5];   // (16,1024)
  const float* ln_w   = (const float*)d_in[6];
  const float* ln_b   = (const float*)d_in[7];
  const float* W_los  = (const float*)d_in[8];   // (1024,10)
  const float* b_los  = (const float*)d_in[9];
  const float* true_y = (const float*)d_in[10];  // (64,10)
  // d_in[11] task_index: unused by the computation
  float* out = (float*)d_out;
  char* ws = (char*)d_ws;

  int*   tk_idx   = (int*)  (ws + WS_TKIDX);
  float* tk_gates = (float*)(ws + WS_TKGATE);
  int*   counts   = (int*)  (ws + WS_COUNTS);
  int*   offsets  = (int*)  (ws + WS_OFFSETS);
  int*   cursors  = (int*)  (ws + WS_CURSORS);
  float* imp      = (float*)(ws + WS_IMP);
  int*   perm_tok = (int*)  (ws + WS_PERMTOK);
  int*   pair_row = (int*)  (ws + WS_PAIRROW);
  float* Hbuf     = (float*)(ws + WS_H);
  float* Obuf     = (float*)(ws + WS_O);

  init_kernel<<<1, 64, 0, stream>>>(counts, imp);
  gate_kernel<<<256, 256, 0, stream>>>(x, wg, tk_idx, tk_gates, counts, imp);
  scan_loss_kernel<<<1, 64, 0, stream>>>(counts, imp, offsets, cursors, out);
  scatter_kernel<<<16, 256, 0, stream>>>(tk_idx, cursors, perm_tok, pair_row);
  ffn_gemm<1,1><<<dim3(128, 8), 256, 0, stream>>>(x,    W1, b1, Hbuf, offsets, perm_tok);
  ffn_gemm<0,0><<<dim3(128, 8), 256, 0, stream>>>(Hbuf, W2, b2, Obuf, offsets, perm_tok);
  moe_ln_kernel<<<64, 256, 0, stream>>>(Obuf, tk_gates, pair_row, ln_w, ln_b, W_los, b_los, out);
  pred_kernel<<<1, 256, 0, stream>>>(true_y, out);
}

// Round 3
// 531.455 us; speedup vs baseline: 1.8737x; 1.8737x over previous
//
#include <hip/hip_runtime.h>
#include <hip/hip_bf16.h>

// Problem constants (from reference)
#define D_DIM 1024
#define H_DIMN 1024
#define N_TOK 1024   // B*M = 64*16
#define N_EXP 16
#define TOPK  4
#define N_PAIR (N_TOK*TOPK)   // 4096
#define B_SZ  64
#define OUT_SZ 10

typedef __attribute__((ext_vector_type(8))) short short8_t;   // 8 bf16 (4 VGPRs)
typedef __attribute__((ext_vector_type(4))) float f32x4;

// ---------------- workspace layout (bytes) ----------------
static constexpr size_t WS_TKIDX   = 0;         // int[4096]
static constexpr size_t WS_TKGATE  = 16384;     // float[4096]
static constexpr size_t WS_COUNTS  = 32768;     // int[16]
static constexpr size_t WS_OFFSETS = 33024;     // int[17]
static constexpr size_t WS_CURSORS = 33280;     // int[16]
static constexpr size_t WS_IMP     = 33536;     // float[16]
static constexpr size_t WS_PERMTOK = 33792;     // int[4096]
static constexpr size_t WS_PAIRROW = 50176;     // int[4096]
static constexpr size_t WS_H       = 131072;                         // float[4096*1024]
static constexpr size_t WS_O       = WS_H + (size_t)N_PAIR*H_DIMN*4; // float[4096*1024]

// ---------------- helpers: fp32 -> bf16 split ----------------
__device__ __forceinline__ unsigned short f2bf_rn(float f) {
  unsigned int u = __float_as_uint(f);
  unsigned int r = (u + 0x7fffu + ((u >> 16) & 1u)) >> 16;
  return (unsigned short)r;
}
__device__ __forceinline__ void splitf(float f, short& h, short& l) {
  unsigned short hu = f2bf_rn(f);
  float fh = __uint_as_float(((unsigned int)hu) << 16);
  unsigned short lu = f2bf_rn(f - fh);
  h = (short)hu; l = (short)lu;
}

// ---------------- init: zero atomics ----------------
__global__ __launch_bounds__(64) void init_kernel(int* counts, float* imp) {
  int t = threadIdx.x;
  if (t < N_EXP) { counts[t] = 0; imp[t] = 0.f; }
}

// ---------------- gating: logits -> top4 -> softmax ----------------
// one wave per token; 4 waves per block; grid 256
__global__ __launch_bounds__(256) void gate_kernel(
    const float* __restrict__ x, const float* __restrict__ wg,
    int* __restrict__ tk_idx, float* __restrict__ tk_gates,
    int* __restrict__ counts, float* __restrict__ imp)
{
  int wave = threadIdx.x >> 6, lane = threadIdx.x & 63;
  int n = blockIdx.x * 4 + wave;
  const float* xr = x + (size_t)n * D_DIM;
  float xv[16];
  #pragma unroll
  for (int i = 0; i < 16; i++) xv[i] = xr[lane + 64*i];

  float lg[N_EXP];
  #pragma unroll
  for (int e = 0; e < N_EXP; e++) lg[e] = 0.f;
  #pragma unroll
  for (int i = 0; i < 16; i++) {
    float xvi = xv[i];
    const float4* wrow = (const float4*)(wg + (size_t)(lane + 64*i) * N_EXP);
    float4 w0 = wrow[0], w1 = wrow[1], w2 = wrow[2], w3 = wrow[3];
    lg[0]  = fmaf(xvi, w0.x, lg[0]);  lg[1]  = fmaf(xvi, w0.y, lg[1]);
    lg[2]  = fmaf(xvi, w0.z, lg[2]);  lg[3]  = fmaf(xvi, w0.w, lg[3]);
    lg[4]  = fmaf(xvi, w1.x, lg[4]);  lg[5]  = fmaf(xvi, w1.y, lg[5]);
    lg[6]  = fmaf(xvi, w1.z, lg[6]);  lg[7]  = fmaf(xvi, w1.w, lg[7]);
    lg[8]  = fmaf(xvi, w2.x, lg[8]);  lg[9]  = fmaf(xvi, w2.y, lg[9]);
    lg[10] = fmaf(xvi, w2.z, lg[10]); lg[11] = fmaf(xvi, w2.w, lg[11]);
    lg[12] = fmaf(xvi, w3.x, lg[12]); lg[13] = fmaf(xvi, w3.y, lg[13]);
    lg[14] = fmaf(xvi, w3.z, lg[14]); lg[15] = fmaf(xvi, w3.w, lg[15]);
  }
  #pragma unroll
  for (int e = 0; e < N_EXP; e++) {
    float s = lg[e];
    #pragma unroll
    for (int off = 32; off; off >>= 1) s += __shfl_xor(s, off);
    lg[e] = s;
  }

  // top-4; ties -> smallest index (matches jax.lax.top_k)
  float tv[TOPK]; int ti[TOPK];
  #pragma unroll
  for (int k = 0; k < TOPK; k++) {
    float mv = -3.4e38f; int mi = 0;
    #pragma unroll
    for (int e = 0; e < N_EXP; e++) if (lg[e] > mv) { mv = lg[e]; mi = e; }
    tv[k] = mv; ti[k] = mi; lg[mi] = -3.4e38f;
  }
  float mx = tv[0];
  float ex[TOPK]; float ssum = 0.f;
  #pragma unroll
  for (int k = 0; k < TOPK; k++) { ex[k] = expf(tv[k] - mx); ssum += ex[k]; }
  float inv = 1.f / ssum;

  if (lane < TOPK) {
    tk_idx  [n*TOPK + lane] = ti[lane];
    tk_gates[n*TOPK + lane] = ex[lane] * inv;
  }
  if (lane == 0) {
    #pragma unroll
    for (int k = 0; k < TOPK; k++) {
      atomicAdd(&counts[ti[k]], 1);
      atomicAdd(&imp[ti[k]], ex[k] * inv);
    }
  }
}

// ---------------- scan offsets + aux loss ----------------
__global__ __launch_bounds__(64) void scan_loss_kernel(
    const int* __restrict__ counts, const float* __restrict__ imp,
    int* __restrict__ offsets, int* __restrict__ cursors, float* __restrict__ out)
{
  if (threadIdx.x == 0) {
    int off = 0;
    for (int e = 0; e < N_EXP; e++) { offsets[e] = off; cursors[e] = off; off += counts[e]; }
    offsets[N_EXP] = off;
    float mi = 0.f, ml = 0.f;
    for (int e = 0; e < N_EXP; e++) { mi += imp[e]; ml += (float)counts[e]; }
    mi *= (1.f/N_EXP); ml *= (1.f/N_EXP);
    float vi = 0.f, vl = 0.f;
    for (int e = 0; e < N_EXP; e++) {
      float di = imp[e] - mi;           vi += di*di;
      float dl = (float)counts[e] - ml; vl += dl*dl;
    }
    vi *= (1.f/(N_EXP-1)); vl *= (1.f/(N_EXP-1));   // ddof=1
    out[640] = 0.01f * (vi/(mi*mi + 1e-10f) + vl/(ml*ml + 1e-10f));
  }
}

// ---------------- scatter tokens into expert-grouped rows ----------------
__global__ __launch_bounds__(256) void scatter_kernel(
    const int* __restrict__ tk_idx, int* __restrict__ cursors,
    int* __restrict__ perm_tok, int* __restrict__ pair_row)
{
  int p = blockIdx.x * 256 + threadIdx.x;   // 0..4095
  int e = tk_idx[p];
  int row = atomicAdd(&cursors[e], 1);
  perm_tok[row] = p >> 2;
  pair_row[p] = row;
}

// ---------------- grouped split-bf16 MFMA GEMM ----------------
// C[rows,1024] = A[rows,1024] @ W[e] + bias[e]  via 3-product bf16 split:
//   C ~= Ah*Bh + Ah*Bl + Al*Bh   (fp32-comparable accuracy, MFMA rate)
// tile 128x128, BK=32, 256 thr = 4 waves (2x2), 4x4 frags of 16x16x32 per wave.
// LDS row stride 40 shorts (80 B = 16*5): bank-quad stride 5 is coprime with 8
// -> A/B stage writes and b128 frag reads all land at 2-way aliasing (free);
// 40 KB total.
template<int GATHER, int RELU>
__global__ __launch_bounds__(256) void ffn_gemm(
    const float* __restrict__ Asrc,
    const float* __restrict__ W,
    const float* __restrict__ bias,
    float* __restrict__ Out,
    const int* __restrict__ offsets,
    const int* __restrict__ perm_tok)
{
  __shared__ short Ah[128][40];
  __shared__ short Al[128][40];
  __shared__ short Bh[128][40];
  __shared__ short Bl[128][40];

  const int e    = blockIdx.x >> 3;
  const int slot = blockIdx.x & 7;
  const int colbase = blockIdx.y * 128;
  const int row0 = offsets[e], row_end = offsets[e+1];
  const int row_start = row0 + slot * 128;
  if (row_start >= row_end) return;
  const int rows_here = min(128, row_end - row_start);

  const int tid = threadIdx.x;

  // A staging: thread -> (row = tid/2, 16 consecutive k at (tid&1)*16)
  const int arow = tid >> 1;
  const int akc  = (tid & 1) * 16;
  int ar = min(arow, rows_here - 1);
  int asrc_row = row_start + ar;
  if (GATHER) asrc_row = perm_tok[asrc_row];
  const float* a_base = Asrc + (size_t)asrc_row * D_DIM + akc;

  // B staging: thread -> (col n = tid&127, 16 consecutive k at (tid>>7)*16)
  const int bn  = tid & 127;
  const int bkg = tid >> 7;
  const float* b_base = W + (size_t)e * D_DIM * H_DIMN
                          + (size_t)(bkg * 16) * H_DIMN + colbase + bn;

  // wave / fragment coords
  const int lane = tid & 63;
  const int wid  = tid >> 6;
  const int wr = wid >> 1, wc = wid & 1;
  const int l16 = lane & 15, l4 = lane >> 4;
  const int koff = l4 * 8;              // element offset into BK=32
  const int ar0 = wr * 64 + l16;
  const int br0 = wc * 64 + l16;

  f32x4 acc[4][4];
  #pragma unroll
  for (int i = 0; i < 4; i++)
    #pragma unroll
    for (int j = 0; j < 4; j++) acc[i][j] = (f32x4)(0.f);

  float4 apre[4];
  float  bpre[16];
  // prologue loads (kk = 0)
  #pragma unroll
  for (int i = 0; i < 4; i++) apre[i] = *(const float4*)(a_base + 4*i);
  #pragma unroll
  for (int i = 0; i < 16; i++) bpre[i] = b_base[(size_t)i * H_DIMN];

  for (int kk = 0; kk < D_DIM; kk += 32) {
    __syncthreads();   // previous tile's consumers done

    // ---- convert + stage A ----
    {
      short8_t h0, h1, l0, l1;
      #pragma unroll
      for (int i = 0; i < 4; i++) {
        float v[4] = {apre[i].x, apre[i].y, apre[i].z, apre[i].w};
        #pragma unroll
        for (int j = 0; j < 4; j++) {
          int idx = i*4 + j;
          short hs, ls; splitf(v[j], hs, ls);
          if (idx < 8) { h0[idx] = hs; l0[idx] = ls; }
          else         { h1[idx-8] = hs; l1[idx-8] = ls; }
        }
      }
      *(short8_t*)&Ah[arow][akc]     = h0;
      *(short8_t*)&Ah[arow][akc + 8] = h1;
      *(short8_t*)&Al[arow][akc]     = l0;
      *(short8_t*)&Al[arow][akc + 8] = l1;
    }
    // ---- convert + stage B (register transpose: 16 k's at one n) ----
    {
      short8_t h0, h1, l0, l1;
      #pragma unroll
      for (int i = 0; i < 16; i++) {
        short hs, ls; splitf(bpre[i], hs, ls);
        if (i < 8) { h0[i] = hs; l0[i] = ls; }
        else       { h1[i-8] = hs; l1[i-8] = ls; }
      }
      *(short8_t*)&Bh[bn][bkg*16]     = h0;
      *(short8_t*)&Bh[bn][bkg*16 + 8] = h1;
      *(short8_t*)&Bl[bn][bkg*16]     = l0;
      *(short8_t*)&Bl[bn][bkg*16 + 8] = l1;
    }

    // prefetch next K-step NOW (apre/bpre regs are dead after the converts
    // above; issuing before the barrier lets the loads fly during the
    // barrier + fragment reads + MFMA phase)
    if (kk + 32 < D_DIM) {
      #pragma unroll
      for (int i = 0; i < 4; i++) apre[i] = *(const float4*)(a_base + kk + 32 + 4*i);
      #pragma unroll
      for (int i = 0; i < 16; i++) bpre[i] = b_base[(size_t)(kk + 32 + i) * H_DIMN];
    }

    __syncthreads();   // tiles ready

    // ---- fragments + 48 MFMAs ----
    short8_t AHf[4], ALf[4], BHf[4], BLf[4];
    #pragma unroll
    for (int m = 0; m < 4; m++) {
      AHf[m] = *(const short8_t*)&Ah[ar0 + m*16][koff];
      ALf[m] = *(const short8_t*)&Al[ar0 + m*16][koff];
    }
    #pragma unroll
    for (int n = 0; n < 4; n++) {
      BHf[n] = *(const short8_t*)&Bh[br0 + n*16][koff];
      BLf[n] = *(const short8_t*)&Bl[br0 + n*16][koff];
    }
    #pragma unroll
    for (int n = 0; n < 4; n++)
      #pragma unroll
      for (int m = 0; m < 4; m++)
        acc[m][n] = __builtin_amdgcn_mfma_f32_16x16x32_bf16(AHf[m], BHf[n], acc[m][n], 0, 0, 0);
    #pragma unroll
    for (int n = 0; n < 4; n++)
      #pragma unroll
      for (int m = 0; m < 4; m++)
        acc[m][n] = __builtin_amdgcn_mfma_f32_16x16x32_bf16(AHf[m], BLf[n], acc[m][n], 0, 0, 0);
    #pragma unroll
    for (int n = 0; n < 4; n++)
      #pragma unroll
      for (int m = 0; m < 4; m++)
        acc[m][n] = __builtin_amdgcn_mfma_f32_16x16x32_bf16(ALf[m], BHf[n], acc[m][n], 0, 0, 0);
  }

  // ---- epilogue: bias (+relu), scattered dword stores ----
  float bvals[4];
  #pragma unroll
  for (int n = 0; n < 4; n++)
    bvals[n] = bias[e * H_DIMN + colbase + wc*64 + n*16 + l16];

  #pragma unroll
  for (int m = 0; m < 4; m++) {
    #pragma unroll
    for (int n = 0; n < 4; n++) {
      const int col = colbase + wc*64 + n*16 + l16;
      #pragma unroll
      for (int j = 0; j < 4; j++) {
        int lr = wr*64 + m*16 + l4*4 + j;
        if (lr < rows_here) {
          float v = acc[m][n][j] + bvals[n];
          if (RELU) v = fmaxf(v, 0.f);
          Out[(size_t)(row_start + lr) * H_DIMN + col] = v;
        }
      }
    }
  }
}

// ---------------- gather per-token, sum over M, LayerNorm, scores head ----------------
__global__ __launch_bounds__(256) void moe_ln_kernel(
    const float* __restrict__ O,
    const float* __restrict__ tk_gates,
    const int* __restrict__ pair_row,
    const float* __restrict__ ln_w, const float* __restrict__ ln_b,
    const float* __restrict__ W_los, const float* __restrict__ b_los,
    float* __restrict__ out)
{
  __shared__ float fin[D_DIM];
  __shared__ float redx[256];
  __shared__ float redy[256];
  const int b = blockIdx.x, tid = threadIdx.x;
  float4 acc = make_float4(0.f,0.f,0.f,0.f);
  for (int m = 0; m < 16; m++) {
    int n = b*16 + m;
    #pragma unroll
    for (int k = 0; k < TOPK; k++) {
      int p = n*TOPK + k;
      float g = tk_gates[p];
      int row = pair_row[p];
      float4 v = *(const float4*)&O[(size_t)row*D_DIM + tid*4];
      acc.x = fmaf(g, v.x, acc.x);
      acc.y = fmaf(g, v.y, acc.y);
      acc.z = fmaf(g, v.z, acc.z);
      acc.w = fmaf(g, v.w, acc.w);
    }
  }
  float s  = acc.x + acc.y + acc.z + acc.w;
  float s2 = acc.x*acc.x + acc.y*acc.y + acc.z*acc.z + acc.w*acc.w;
  redx[tid] = s; redy[tid] = s2;
  __syncthreads();
  for (int off = 128; off > 0; off >>= 1) {
    if (tid < off) { redx[tid] += redx[tid+off]; redy[tid] += redy[tid+off]; }
    __syncthreads();
  }
  float mean = redx[0] * (1.f/D_DIM);
  float var  = redy[0] * (1.f/D_DIM) - mean*mean;   // ddof=0
  float rstd = rsqrtf(var + 1e-5f);

  int d0 = tid*4;
  fin[d0+0] = (acc.x - mean)*rstd*ln_w[d0+0] + ln_b[d0+0];
  fin[d0+1] = (acc.y - mean)*rstd*ln_w[d0+1] + ln_b[d0+1];
  fin[d0+2] = (acc.z - mean)*rstd*ln_w[d0+2] + ln_b[d0+2];
  fin[d0+3] = (acc.w - mean)*rstd*ln_w[d0+3] + ln_b[d0+3];
  __syncthreads();

  if (tid < 64) {
    for (int o = 0; o < OUT_SZ; o++) {
      float p = 0.f;
      for (int d = tid; d < D_DIM; d += 64) p = fmaf(fin[d], W_los[d*OUT_SZ + o], p);
      #pragma unroll
      for (int off = 32; off; off >>= 1) p += __shfl_xor(p, off);
      if (tid == 0) out[b*OUT_SZ + o] = p + b_los[o];
    }
  }
}

// ---------------- pred_loss = mean((scores - true_y)^2) ----------------
__global__ __launch_bounds__(256) void pred_kernel(
    const float* __restrict__ true_y, float* __restrict__ out)
{
  __shared__ float red[256];
  int tid = threadIdx.x;
  float s = 0.f;
  for (int i = tid; i < B_SZ*OUT_SZ; i += 256) {
    float df = out[i] - true_y[i];
    s = fmaf(df, df, s);
  }
  red[tid] = s;
  __syncthreads();
  for (int off = 128; off > 0; off >>= 1) {
    if (tid < off) red[tid] += red[tid+off];
    __syncthreads();
  }
  if (tid == 0) out[641] = red[0] * (1.f/(B_SZ*OUT_SZ));
}

// ---------------- launch ----------------
extern "C" void kernel_launch(void* const* d_in, const int* in_sizes, int n_in,
                              void* d_out, int out_size, void* d_ws, size_t ws_size,
                              hipStream_t stream) {
  const float* x      = (const float*)d_in[0];
  const float* wg     = (const float*)d_in[1];
  const float* W1     = (const float*)d_in[2];
  const float* b1     = (const float*)d_in[3];
  const float* W2     = (const float*)d_in[4];
  const float* b2     = (const float*)d_in[5];
  const float* ln_w   = (const float*)d_in[6];
  const float* ln_b   = (const float*)d_in[7];
  const float* W_los  = (const float*)d_in[8];
  const float* b_los  = (const float*)d_in[9];
  const float* true_y = (const float*)d_in[10];
  float* out = (float*)d_out;
  char* ws = (char*)d_ws;

  int*   tk_idx   = (int*)  (ws + WS_TKIDX);
  float* tk_gates = (float*)(ws + WS_TKGATE);
  int*   counts   = (int*)  (ws + WS_COUNTS);
  int*   offsets  = (int*)  (ws + WS_OFFSETS);
  int*   cursors  = (int*)  (ws + WS_CURSORS);
  float* imp      = (float*)(ws + WS_IMP);
  int*   perm_tok = (int*)  (ws + WS_PERMTOK);
  int*   pair_row = (int*)  (ws + WS_PAIRROW);
  float* Hbuf     = (float*)(ws + WS_H);
  float* Obuf     = (float*)(ws + WS_O);

  init_kernel<<<1, 64, 0, stream>>>(counts, imp);
  gate_kernel<<<256, 256, 0, stream>>>(x, wg, tk_idx, tk_gates, counts, imp);
  scan_loss_kernel<<<1, 64, 0, stream>>>(counts, imp, offsets, cursors, out);
  scatter_kernel<<<16, 256, 0, stream>>>(tk_idx, cursors, perm_tok, pair_row);
  ffn_gemm<1,1><<<dim3(128, 8), 256, 0, stream>>>(x,    W1, b1, Hbuf, offsets, perm_tok);
  ffn_gemm<0,0><<<dim3(128, 8), 256, 0, stream>>>(Hbuf, W2, b2, Obuf, offsets, perm_tok);
  moe_ln_kernel<<<64, 256, 0, stream>>>(Obuf, tk_gates, pair_row, ln_w, ln_b, W_los, b_los, out);
  pred_kernel<<<1, 256, 0, stream>>>(true_y, out);
}